// Round 10
// baseline (20252.019 us; speedup 1.0000x reference)
//
#include <hip/hip_runtime.h>
#include <hip/hip_bf16.h>
#include <hip/hip_cooperative_groups.h>

typedef __attribute__((ext_vector_type(8))) short short8;
typedef __attribute__((ext_vector_type(4))) float f32x4;
typedef __attribute__((ext_vector_type(4))) unsigned short ushort4_t;
typedef unsigned long long u64;

#define BB 8
#define SS 2048
#define DD 1024
#define EE 4096
#define NB 64

__device__ __forceinline__ unsigned short f2bf(float f) {
  unsigned int u = __builtin_bit_cast(unsigned int, f);
  u += 0x7fffu + ((u >> 16) & 1u);
  return (unsigned short)(u >> 16);
}
__device__ __forceinline__ float bf2f(unsigned short h) {
  unsigned int u = ((unsigned int)h) << 16;
  return __builtin_bit_cast(float, u);
}

// ---------------- Kernel 1: cast W_w and U_w fp32 -> bf16 ----------------
__global__ void cvt2_kernel(const float* __restrict__ Wf, const float* __restrict__ Uf,
                            unsigned short* __restrict__ Wb, unsigned short* __restrict__ Ub) {
  const int n4 = EE * DD / 4;
  for (int i = blockIdx.x * blockDim.x + threadIdx.x; i < n4; i += gridDim.x * blockDim.x) {
    float4 w = ((const float4*)Wf)[i];
    float4 u = ((const float4*)Uf)[i];
    ushort4_t wo, uo;
    wo[0] = f2bf(w.x); wo[1] = f2bf(w.y); wo[2] = f2bf(w.z); wo[3] = f2bf(w.w);
    uo[0] = f2bf(u.x); uo[1] = f2bf(u.y); uo[2] = f2bf(u.z); uo[3] = f2bf(u.w);
    ((ushort4_t*)Wb)[i] = wo;
    ((ushort4_t*)Ub)[i] = uo;
  }
}

// ---------------- Kernel 2: LayerNorm -> bf16 h_out ----------------
__global__ void ln_kernel(const float* __restrict__ x, const float* __restrict__ gamma,
                          const float* __restrict__ beta, unsigned short* __restrict__ hout) {
  int row = blockIdx.x;
  int t = threadIdx.x;
  int wid = t >> 6, lane = t & 63;
  float4 v = ((const float4*)(x + (size_t)row * DD))[t];
  float s = v.x + v.y + v.z + v.w;
  float s2 = v.x * v.x + v.y * v.y + v.z * v.z + v.w * v.w;
  for (int o = 32; o; o >>= 1) { s += __shfl_down(s, o); s2 += __shfl_down(s2, o); }
  __shared__ float rs[4], rq[4];
  if (lane == 0) { rs[wid] = s; rq[wid] = s2; }
  __syncthreads();
  float sum = rs[0] + rs[1] + rs[2] + rs[3];
  float sum2 = rq[0] + rq[1] + rq[2] + rq[3];
  float mean = sum * (1.0f / DD);
  float var = sum2 * (1.0f / DD) - mean * mean;
  float rstd = rsqrtf(var + 1e-5f);
  float4 g = ((const float4*)gamma)[t];
  float4 bt = ((const float4*)beta)[t];
  ushort4_t o4;
  o4[0] = f2bf((v.x - mean) * rstd * g.x + bt.x);
  o4[1] = f2bf((v.y - mean) * rstd * g.y + bt.y);
  o4[2] = f2bf((v.z - mean) * rstd * g.z + bt.z);
  o4[3] = f2bf((v.w - mean) * rstd * g.w + bt.w);
  ((ushort4_t*)(hout + (size_t)row * DD))[t] = o4;
}

// ---------------- Kernel 3: GEMM xW = hout . W_w^T + b, 64 rows/block ----------------
__launch_bounds__(256)
__global__ void gemm_xw(const unsigned short* __restrict__ A, const unsigned short* __restrict__ Bm,
                        const float* __restrict__ bias, unsigned short* __restrict__ xw) {
  int rowTile = blockIdx.x;   // 0..255, 64 rows each
  int colGrp = blockIdx.y;    // 0..15
  int wid = threadIdx.x >> 6;
  int lane = threadIdx.x & 63;
  int colBase = colGrp * 256 + wid * 64;
  int r0 = rowTile * 64 + (lane & 15);
  int kb = (lane >> 4) * 8;
  f32x4 acc[4][4] = {};
  for (int k0 = 0; k0 < DD; k0 += 32) {
    short8 af[4];
#pragma unroll
    for (int rr = 0; rr < 4; rr++)
      af[rr] = *(const short8*)(A + (size_t)(r0 + rr * 16) * DD + k0 + kb);
#pragma unroll
    for (int c = 0; c < 4; c++) {
      int col = colBase + c * 16 + (lane & 15);
      short8 bf = *(const short8*)(Bm + (size_t)col * DD + k0 + kb);
#pragma unroll
      for (int rr = 0; rr < 4; rr++)
        acc[rr][c] = __builtin_amdgcn_mfma_f32_16x16x32_bf16(af[rr], bf, acc[rr][c], 0, 0, 0);
    }
  }
#pragma unroll
  for (int rr = 0; rr < 4; rr++) {
#pragma unroll
    for (int c = 0; c < 4; c++) {
      int col = colBase + c * 16 + (lane & 15);
      float bv = bias[col];
#pragma unroll
      for (int r2 = 0; r2 < 4; r2++) {
        int R = rowTile * 64 + rr * 16 + (lane >> 4) * 4 + r2;
        int b = R >> 11, sIdx = R & 2047;
        xw[(size_t)sIdx * (BB * EE) + (size_t)b * EE + col] = f2bf(acc[rr][c][r2] + bv);
      }
    }
  }
}

// ---------------- Kernel 4: sLSTM scan — flag sync; DIRECT global MFMA fragments ----------------
// 64 blocks x 256 thr (4 waves). Block bl owns d in [bl*16, bl*16+16).
// Wave g owns gate g (16 e-cols), U slice register-resident.
// R7-proven protocol (coherent relaxed agent atomics, vmcnt(0) release, barrier,
// flag). New: no LDS h-staging — A-fragments are 16B-contiguous in global h,
// loaded straight from L3 as coherent u64 pairs after the flag poll.
__launch_bounds__(256, 1)
__global__ void scan_kernel(const unsigned short* __restrict__ xw, const unsigned short* __restrict__ Ub,
                            const float* __restrict__ x, float* __restrict__ out,
                            unsigned short* __restrict__ hbuf, int* __restrict__ flags) {
  int bl = blockIdx.x;
  int tid = threadIdx.x;
  int wid = tid >> 6, lane = tid & 63;
  int d0 = bl * 16;

  __shared__ float g_lds[4][8][16];
  __shared__ char pad_lds[80 * 1024];   // occupancy limiter: 1 block/CU -> big reg budget
  ((volatile char*)pad_lds)[tid] = 0;   // keep allocation alive

  // preload U fragments: wave wid, e-cols wid*1024 + d0 + 0..15 -> 32 x short8
  int ecol = wid * 1024 + d0 + (lane & 15);
  int kb = (lane >> 4) * 8;
  short8 u[32];
#pragma unroll
  for (int kk = 0; kk < 32; kk++)
    u[kk] = *(const short8*)(Ub + (size_t)ecol * DD + kk * 32 + kb);
#pragma unroll
  for (int kk = 0; kk < 32; kk++)
    asm volatile("" : "+v"(u[kk]));  // pin; forbid remat/reload

  float c_s = 0.0f, n_s = 1.0f;
  int ub = tid >> 4, ud = tid & 15;  // update-thread coords (tid < 128)
  bool upd = tid < BB * 16;
  int arow = lane & 7;               // A rows 8..15 duplicate 0..7 (C rows 8..15 unused)
  int bq = (lane >> 4) * 4;          // C-frag batch base
  int qbase = arow * 256 + (lane >> 4) * 2;  // fragment base qword within h slot

  for (int s = 0; s < SS; s++) {
    // ---- prefetch step-s operands (independent of h) before the poll ----
    const unsigned short* xwp = xw + (size_t)s * (BB * EE) + (size_t)wid * 1024 + d0 + (lane & 15);
    unsigned short xv[4] = {0, 0, 0, 0};
    if (bq < BB) {
#pragma unroll
      for (int r2 = 0; r2 < 4; r2++) xv[r2] = xwp[(size_t)(bq + r2) * EE];
    }
    float xin = 0.0f;
    size_t oi = 0;
    if (upd) {
      oi = (size_t)ub * (SS * DD) + (size_t)s * DD + d0 + ud;
      xin = x[oi];
    }

    // ---- one-sided wait: all 64 flags >= s; two-deep pipelined poll ----
    if (s != 0) {
      const int* fp = flags + lane * 32;
      int f0 = __hip_atomic_load(fp, __ATOMIC_RELAXED, __HIP_MEMORY_SCOPE_AGENT);
      int f1 = __hip_atomic_load(fp, __ATOMIC_RELAXED, __HIP_MEMORY_SCOPE_AGENT);
      for (;;) {
        if (!__any(f0 < s)) break;     // test older sample while newer is in flight
        f0 = f1;
        f1 = __hip_atomic_load(fp, __ATOMIC_RELAXED, __HIP_MEMORY_SCOPE_AGENT);
      }
    }
    asm volatile("" ::: "memory");     // no hoisting of h loads above the poll

    // ---- A-fragments of h_s straight from L3: 64 coherent u64 loads ----
    const u64* hb = (const u64*)hbuf + (size_t)(s & 1) * 2048;
    short8 fr[32];
#pragma unroll
    for (int kk = 0; kk < 32; kk++) {
      union { u64 q[2]; short8 v; } cvt;
      cvt.q[0] = __hip_atomic_load(hb + qbase + kk * 8, __ATOMIC_RELAXED, __HIP_MEMORY_SCOPE_AGENT);
      cvt.q[1] = __hip_atomic_load(hb + qbase + kk * 8 + 1, __ATOMIC_RELAXED, __HIP_MEMORY_SCOPE_AGENT);
      fr[kk] = cvt.v;
    }

    // ---- gates = h @ U^T : 32 MFMAs, 4 independent chains ----
    f32x4 a0 = {}, a1 = {}, a2 = {}, a3 = {};
#pragma unroll
    for (int kk = 0; kk < 32; kk += 4) {
      a0 = __builtin_amdgcn_mfma_f32_16x16x32_bf16(fr[kk + 0], u[kk + 0], a0, 0, 0, 0);
      a1 = __builtin_amdgcn_mfma_f32_16x16x32_bf16(fr[kk + 1], u[kk + 1], a1, 0, 0, 0);
      a2 = __builtin_amdgcn_mfma_f32_16x16x32_bf16(fr[kk + 2], u[kk + 2], a2, 0, 0, 0);
      a3 = __builtin_amdgcn_mfma_f32_16x16x32_bf16(fr[kk + 3], u[kk + 3], a3, 0, 0, 0);
    }
    f32x4 acc = (a0 + a1) + (a2 + a3);

    // ---- publish gates (valid batches) ----
    if (bq < BB) {
#pragma unroll
      for (int r2 = 0; r2 < 4; r2++)
        g_lds[wid][bq + r2][lane & 15] = acc[r2] + bf2f(xv[r2]);
    }
    __syncthreads();

    // ---- state update (128 thr, 1 d each) + coherent h publish; release = vmcnt(0) ----
    float h_val = 0.0f;
    if (upd) {
      float gi = g_lds[0][ub][ud], gf = g_lds[1][ub][ud];
      float go = g_lds[2][ub][ud], gz = g_lds[3][ub][ud];
      float it = __expf(gi);
      float ft = 1.0f / (1.0f + __expf(-gf));
      float ot = 1.0f / (1.0f + __expf(-go));
      float az = fabsf(gz);
      float e2 = __expf(2.0f * az);
      float zt = __builtin_copysignf(1.0f - 2.0f / (e2 + 1.0f), gz);
      c_s = ft * c_s + it * zt;
      n_s = ft * n_s + it;
      h_val = ot * (c_s / (n_s + 1e-6f));
      __hip_atomic_store(hbuf + (size_t)((s + 1) & 1) * (BB * DD) + ub * DD + d0 + ud,
                         f2bf(h_val), __ATOMIC_RELAXED, __HIP_MEMORY_SCOPE_AGENT);
      asm volatile("s_waitcnt vmcnt(0)" ::: "memory");  // drain coherent h stores
    }
    __syncthreads();     // all waves joined after stores drained
    if (tid == 0)
      __hip_atomic_store(flags + bl * 32, s + 1, __ATOMIC_RELAXED, __HIP_MEMORY_SCOPE_AGENT);
    // ---- fused output write: off the cross-block critical path ----
    if (upd)
      __builtin_nontemporal_store(xin + h_val, out + oi);
  }
}

// ---------------- launch ----------------
extern "C" void kernel_launch(void* const* d_in, const int* in_sizes, int n_in,
                              void* d_out, int out_size, void* d_ws, size_t ws_size,
                              hipStream_t stream) {
  const float* xp = (const float*)d_in[0];
  const float* Wwf = (const float*)d_in[1];
  const float* Wbias = (const float*)d_in[2];
  const float* Uwf = (const float*)d_in[3];
  const float* gamma = (const float*)d_in[4];
  const float* beta = (const float*)d_in[5];
  float* outp = (float*)d_out;

  char* w = (char*)d_ws;
  unsigned short* Wb = (unsigned short*)(w);                 // 8 MB
  unsigned short* Ub = (unsigned short*)(w + 8388608);       // 8 MB
  unsigned short* hout = (unsigned short*)(w + 16777216);    // 32 MB
  unsigned short* xw = (unsigned short*)(w + 50331648);      // 128 MB
  unsigned short* hbuf = (unsigned short*)(w + 184549376);   // 32 KB (2 x 8 x 1024 bf16)
  int* flags = (int*)(w + 184549376 + 32768);                // 64 flags, 128B apart

  hipMemsetAsync((void*)hbuf, 0, 32768 + 8192, stream);      // zero h state + flags every call

  hipLaunchKernelGGL(cvt2_kernel, dim3(1024), dim3(256), 0, stream, Wwf, Uwf, Wb, Ub);
  hipLaunchKernelGGL(ln_kernel, dim3(BB * SS), dim3(256), 0, stream, xp, gamma, beta, hout);
  hipLaunchKernelGGL(gemm_xw, dim3(256, 16), dim3(256), 0, stream, hout, Wb, Wbias, xw);

  void* args[6];
  const unsigned short* xw_c = xw;
  const unsigned short* ub_c = Ub;
  args[0] = (void*)&xw_c;
  args[1] = (void*)&ub_c;
  args[2] = (void*)&xp;
  args[3] = (void*)&outp;
  args[4] = (void*)&hbuf;
  args[5] = (void*)&flags;
  hipLaunchCooperativeKernel((void*)scan_kernel, dim3(NB), dim3(256), args, 0, stream);
}

// Round 11
// 6066.603 us; speedup vs baseline: 3.3383x; 3.3383x over previous
//
#include <hip/hip_runtime.h>
#include <hip/hip_bf16.h>
#include <hip/hip_cooperative_groups.h>

typedef __attribute__((ext_vector_type(8))) short short8;
typedef __attribute__((ext_vector_type(4))) float f32x4;
typedef __attribute__((ext_vector_type(4))) unsigned short ushort4_t;

#define BB 8
#define SS 2048
#define DD 1024
#define EE 4096
#define NB 64

__device__ __forceinline__ unsigned short f2bf(float f) {
  unsigned int u = __builtin_bit_cast(unsigned int, f);
  u += 0x7fffu + ((u >> 16) & 1u);
  return (unsigned short)(u >> 16);
}
__device__ __forceinline__ float bf2f(unsigned short h) {
  unsigned int u = ((unsigned int)h) << 16;
  return __builtin_bit_cast(float, u);
}

// ---------------- Kernel 1: cast W_w and U_w fp32 -> bf16 ----------------
__global__ void cvt2_kernel(const float* __restrict__ Wf, const float* __restrict__ Uf,
                            unsigned short* __restrict__ Wb, unsigned short* __restrict__ Ub) {
  const int n4 = EE * DD / 4;
  for (int i = blockIdx.x * blockDim.x + threadIdx.x; i < n4; i += gridDim.x * blockDim.x) {
    float4 w = ((const float4*)Wf)[i];
    float4 u = ((const float4*)Uf)[i];
    ushort4_t wo, uo;
    wo[0] = f2bf(w.x); wo[1] = f2bf(w.y); wo[2] = f2bf(w.z); wo[3] = f2bf(w.w);
    uo[0] = f2bf(u.x); uo[1] = f2bf(u.y); uo[2] = f2bf(u.z); uo[3] = f2bf(u.w);
    ((ushort4_t*)Wb)[i] = wo;
    ((ushort4_t*)Ub)[i] = uo;
  }
}

// ---------------- Kernel 2: LayerNorm -> bf16 h_out ----------------
__global__ void ln_kernel(const float* __restrict__ x, const float* __restrict__ gamma,
                          const float* __restrict__ beta, unsigned short* __restrict__ hout) {
  int row = blockIdx.x;
  int t = threadIdx.x;
  int wid = t >> 6, lane = t & 63;
  float4 v = ((const float4*)(x + (size_t)row * DD))[t];
  float s = v.x + v.y + v.z + v.w;
  float s2 = v.x * v.x + v.y * v.y + v.z * v.z + v.w * v.w;
  for (int o = 32; o; o >>= 1) { s += __shfl_down(s, o); s2 += __shfl_down(s2, o); }
  __shared__ float rs[4], rq[4];
  if (lane == 0) { rs[wid] = s; rq[wid] = s2; }
  __syncthreads();
  float sum = rs[0] + rs[1] + rs[2] + rs[3];
  float sum2 = rq[0] + rq[1] + rq[2] + rq[3];
  float mean = sum * (1.0f / DD);
  float var = sum2 * (1.0f / DD) - mean * mean;
  float rstd = rsqrtf(var + 1e-5f);
  float4 g = ((const float4*)gamma)[t];
  float4 bt = ((const float4*)beta)[t];
  ushort4_t o4;
  o4[0] = f2bf((v.x - mean) * rstd * g.x + bt.x);
  o4[1] = f2bf((v.y - mean) * rstd * g.y + bt.y);
  o4[2] = f2bf((v.z - mean) * rstd * g.z + bt.z);
  o4[3] = f2bf((v.w - mean) * rstd * g.w + bt.w);
  ((ushort4_t*)(hout + (size_t)row * DD))[t] = o4;
}

// ---------------- Kernel 3: GEMM xW = hout . W_w^T + b, 64 rows/block ----------------
__launch_bounds__(256)
__global__ void gemm_xw(const unsigned short* __restrict__ A, const unsigned short* __restrict__ Bm,
                        const float* __restrict__ bias, unsigned short* __restrict__ xw) {
  int rowTile = blockIdx.x;   // 0..255, 64 rows each
  int colGrp = blockIdx.y;    // 0..15
  int wid = threadIdx.x >> 6;
  int lane = threadIdx.x & 63;
  int colBase = colGrp * 256 + wid * 64;
  int r0 = rowTile * 64 + (lane & 15);
  int kb = (lane >> 4) * 8;
  f32x4 acc[4][4] = {};
  for (int k0 = 0; k0 < DD; k0 += 32) {
    short8 af[4];
#pragma unroll
    for (int rr = 0; rr < 4; rr++)
      af[rr] = *(const short8*)(A + (size_t)(r0 + rr * 16) * DD + k0 + kb);
#pragma unroll
    for (int c = 0; c < 4; c++) {
      int col = colBase + c * 16 + (lane & 15);
      short8 bf = *(const short8*)(Bm + (size_t)col * DD + k0 + kb);
#pragma unroll
      for (int rr = 0; rr < 4; rr++)
        acc[rr][c] = __builtin_amdgcn_mfma_f32_16x16x32_bf16(af[rr], bf, acc[rr][c], 0, 0, 0);
    }
  }
#pragma unroll
  for (int rr = 0; rr < 4; rr++) {
#pragma unroll
    for (int c = 0; c < 4; c++) {
      int col = colBase + c * 16 + (lane & 15);
      float bv = bias[col];
#pragma unroll
      for (int r2 = 0; r2 < 4; r2++) {
        int R = rowTile * 64 + rr * 16 + (lane >> 4) * 4 + r2;
        int b = R >> 11, sIdx = R & 2047;
        xw[(size_t)sIdx * (BB * EE) + (size_t)b * EE + col] = f2bf(acc[rr][c][r2] + bv);
      }
    }
  }
}

// ---------------- Kernel 4: sLSTM scan — R7 protocol + pre-activated gates ----------------
// 64 blocks x 256 thr (4 waves). Block bl owns d in [bl*16, bl*16+16).
// Wave g owns gate g (16 e-cols), U slice register-resident.
// Proven R7 protocol: coherent relaxed agent atomics, vmcnt(0) release, barrier,
// flag; all-wave poll; LDS h-stage (16 dword loads/thread, XOR swizzle).
// New: each wave applies its gate's nonlinearity BEFORE publishing to g_lds
// (wave-uniform, shortens the serial post-barrier tail).
__launch_bounds__(256, 1)
__global__ void scan_kernel(const unsigned short* __restrict__ xw, const unsigned short* __restrict__ Ub,
                            const float* __restrict__ x, float* __restrict__ out,
                            unsigned short* __restrict__ hbuf, int* __restrict__ flags) {
  int bl = blockIdx.x;
  int tid = threadIdx.x;
  int wid = tid >> 6, lane = tid & 63;
  int d0 = bl * 16;

  __shared__ __align__(16) unsigned short h_lds[8 * 1024];  // 16KB, XOR-swizzled
  __shared__ float g_lds[4][8][16];
  __shared__ char pad_lds[80 * 1024];   // occupancy limiter: 1 block/CU -> big reg budget
  ((volatile char*)pad_lds)[tid] = 0;   // keep allocation alive

  // preload U fragments: wave wid, e-cols wid*1024 + d0 + 0..15 -> 32 x short8
  int ecol = wid * 1024 + d0 + (lane & 15);
  int kb = (lane >> 4) * 8;
  short8 u[32];
#pragma unroll
  for (int kk = 0; kk < 32; kk++)
    u[kk] = *(const short8*)(Ub + (size_t)ecol * DD + kk * 32 + kb);
#pragma unroll
  for (int kk = 0; kk < 32; kk++)
    asm volatile("" : "+v"(u[kk]));  // pin; forbid remat/reload

  float c_s = 0.0f, n_s = 1.0f;
  int ub = tid >> 4, ud = tid & 15;  // update-thread coords (tid < 128)
  bool upd = tid < BB * 16;
  int arow = lane & 7;               // A rows 8..15 duplicate 0..7 (C rows 8..15 unused)
  int bq = (lane >> 4) * 4;          // C-frag batch base

  for (int s = 0; s < SS; s++) {
    // ---- prefetch step-s operands (independent of h) before the poll ----
    const unsigned short* xwp = xw + (size_t)s * (BB * EE) + (size_t)wid * 1024 + d0 + (lane & 15);
    unsigned short xv[4] = {0, 0, 0, 0};
    if (bq < BB) {
#pragma unroll
      for (int r2 = 0; r2 < 4; r2++) xv[r2] = xwp[(size_t)(bq + r2) * EE];
    }
    float xin = 0.0f;
    size_t oi = 0;
    if (upd) {
      oi = (size_t)ub * (SS * DD) + (size_t)s * DD + d0 + ud;
      xin = x[oi];
    }

    // ---- one-sided wait: all 64 block flags >= s (coherent relaxed loads) ----
    if (s != 0) {
      int f = __hip_atomic_load(flags + lane * 32, __ATOMIC_RELAXED, __HIP_MEMORY_SCOPE_AGENT);
      while (__any(f < s)) {
        f = __hip_atomic_load(flags + lane * 32, __ATOMIC_RELAXED, __HIP_MEMORY_SCOPE_AGENT);
      }
    }

    // ---- stage h (8 x 1024 bf16 = 16KB) -> swizzled LDS via coherent dword loads ----
    {
      const unsigned int* hg = (const unsigned int*)(hbuf + (size_t)(s & 1) * (BB * DD));
      unsigned int tmp[16];
#pragma unroll
      for (int i = 0; i < 16; i++)
        tmp[i] = __hip_atomic_load(hg + tid + i * 256, __ATOMIC_RELAXED, __HIP_MEMORY_SCOPE_AGENT);
#pragma unroll
      for (int i = 0; i < 16; i++) {
        int dw = tid + i * 256;              // 0..4095
        int row = dw >> 9;                   // 512 dwords per 2KB row
        int byte = (row * 2048 + (dw & 511) * 4) ^ (row << 4);
        *(unsigned int*)((char*)h_lds + byte) = tmp[i];
      }
    }
    __syncthreads();

    // ---- gates = h @ U^T : 32 MFMAs, 4 independent chains ----
    f32x4 a0 = {}, a1 = {}, a2 = {}, a3 = {};
#pragma unroll
    for (int kk = 0; kk < 32; kk += 4) {
      int base = arow * 2048 + (kk * 32 + kb) * 2;
      short8 f0 = *(const short8*)((char*)h_lds + ((base) ^ (arow << 4)));
      short8 f1 = *(const short8*)((char*)h_lds + ((base + 64) ^ (arow << 4)));
      short8 f2 = *(const short8*)((char*)h_lds + ((base + 128) ^ (arow << 4)));
      short8 f3 = *(const short8*)((char*)h_lds + ((base + 192) ^ (arow << 4)));
      a0 = __builtin_amdgcn_mfma_f32_16x16x32_bf16(f0, u[kk], a0, 0, 0, 0);
      a1 = __builtin_amdgcn_mfma_f32_16x16x32_bf16(f1, u[kk + 1], a1, 0, 0, 0);
      a2 = __builtin_amdgcn_mfma_f32_16x16x32_bf16(f2, u[kk + 2], a2, 0, 0, 0);
      a3 = __builtin_amdgcn_mfma_f32_16x16x32_bf16(f3, u[kk + 3], a3, 0, 0, 0);
    }
    f32x4 acc = (a0 + a1) + (a2 + a3);

    // ---- apply THIS wave's gate nonlinearity, then publish (wave-uniform) ----
    if (bq < BB) {
#pragma unroll
      for (int r2 = 0; r2 < 4; r2++) {
        float v = acc[r2] + bf2f(xv[r2]);
        float t;
        if (wid == 0) {
          t = __expf(v);                           // i -> exp
        } else if (wid == 3) {
          float az = fabsf(v);
          float e2 = __expf(2.0f * az);
          t = __builtin_copysignf(1.0f - 2.0f / (e2 + 1.0f), v);  // z -> tanh
        } else {
          t = 1.0f / (1.0f + __expf(-v));          // f,o -> sigmoid
        }
        g_lds[wid][bq + r2][lane & 15] = t;
      }
    }
    __syncthreads();

    // ---- state update (128 thr, 1 d each): fma-only tail + coherent h publish ----
    float h_val = 0.0f;
    if (upd) {
      float it = g_lds[0][ub][ud], ft = g_lds[1][ub][ud];
      float ot = g_lds[2][ub][ud], zt = g_lds[3][ub][ud];
      c_s = ft * c_s + it * zt;
      n_s = ft * n_s + it;
      h_val = ot * (c_s / (n_s + 1e-6f));
      __hip_atomic_store(hbuf + (size_t)((s + 1) & 1) * (BB * DD) + ub * DD + d0 + ud,
                         f2bf(h_val), __ATOMIC_RELAXED, __HIP_MEMORY_SCOPE_AGENT);
      asm volatile("s_waitcnt vmcnt(0)" ::: "memory");  // drain coherent h stores
    }
    __syncthreads();     // all waves joined after stores drained
    if (tid == 0)
      __hip_atomic_store(flags + bl * 32, s + 1, __ATOMIC_RELAXED, __HIP_MEMORY_SCOPE_AGENT);
    // ---- fused output write: off the cross-block critical path ----
    if (upd)
      __builtin_nontemporal_store(xin + h_val, out + oi);
  }
}

// ---------------- launch ----------------
extern "C" void kernel_launch(void* const* d_in, const int* in_sizes, int n_in,
                              void* d_out, int out_size, void* d_ws, size_t ws_size,
                              hipStream_t stream) {
  const float* xp = (const float*)d_in[0];
  const float* Wwf = (const float*)d_in[1];
  const float* Wbias = (const float*)d_in[2];
  const float* Uwf = (const float*)d_in[3];
  const float* gamma = (const float*)d_in[4];
  const float* beta = (const float*)d_in[5];
  float* outp = (float*)d_out;

  char* w = (char*)d_ws;
  unsigned short* Wb = (unsigned short*)(w);                 // 8 MB
  unsigned short* Ub = (unsigned short*)(w + 8388608);       // 8 MB
  unsigned short* hout = (unsigned short*)(w + 16777216);    // 32 MB
  unsigned short* xw = (unsigned short*)(w + 50331648);      // 128 MB
  unsigned short* hbuf = (unsigned short*)(w + 184549376);   // 32 KB (2 x 8 x 1024 bf16)
  int* flags = (int*)(w + 184549376 + 32768);                // 64 flags, 128B apart

  hipMemsetAsync((void*)hbuf, 0, 32768 + 8192, stream);      // zero h state + flags every call

  hipLaunchKernelGGL(cvt2_kernel, dim3(1024), dim3(256), 0, stream, Wwf, Uwf, Wb, Ub);
  hipLaunchKernelGGL(ln_kernel, dim3(BB * SS), dim3(256), 0, stream, xp, gamma, beta, hout);
  hipLaunchKernelGGL(gemm_xw, dim3(256, 16), dim3(256), 0, stream, hout, Wb, Wbias, xw);

  void* args[6];
  const unsigned short* xw_c = xw;
  const unsigned short* ub_c = Ub;
  args[0] = (void*)&xw_c;
  args[1] = (void*)&ub_c;
  args[2] = (void*)&xp;
  args[3] = (void*)&outp;
  args[4] = (void*)&hbuf;
  args[5] = (void*)&flags;
  hipLaunchCooperativeKernel((void*)scan_kernel, dim3(NB), dim3(256), args, 0, stream);
}

// Round 12
// 5481.157 us; speedup vs baseline: 3.6948x; 1.1068x over previous
//
#include <hip/hip_runtime.h>
#include <hip/hip_bf16.h>
#include <hip/hip_cooperative_groups.h>

typedef __attribute__((ext_vector_type(8))) short short8;
typedef __attribute__((ext_vector_type(4))) float f32x4;
typedef __attribute__((ext_vector_type(4))) unsigned short ushort4_t;

#define BB 8
#define SS 2048
#define DD 1024
#define EE 4096
#define NB 64

__device__ __forceinline__ unsigned short f2bf(float f) {
  unsigned int u = __builtin_bit_cast(unsigned int, f);
  u += 0x7fffu + ((u >> 16) & 1u);
  return (unsigned short)(u >> 16);
}
__device__ __forceinline__ float bf2f(unsigned short h) {
  unsigned int u = ((unsigned int)h) << 16;
  return __builtin_bit_cast(float, u);
}

// ---------------- Kernel 1: cast W_w and U_w fp32 -> bf16 ----------------
__global__ void cvt2_kernel(const float* __restrict__ Wf, const float* __restrict__ Uf,
                            unsigned short* __restrict__ Wb, unsigned short* __restrict__ Ub) {
  const int n4 = EE * DD / 4;
  for (int i = blockIdx.x * blockDim.x + threadIdx.x; i < n4; i += gridDim.x * blockDim.x) {
    float4 w = ((const float4*)Wf)[i];
    float4 u = ((const float4*)Uf)[i];
    ushort4_t wo, uo;
    wo[0] = f2bf(w.x); wo[1] = f2bf(w.y); wo[2] = f2bf(w.z); wo[3] = f2bf(w.w);
    uo[0] = f2bf(u.x); uo[1] = f2bf(u.y); uo[2] = f2bf(u.z); uo[3] = f2bf(u.w);
    ((ushort4_t*)Wb)[i] = wo;
    ((ushort4_t*)Ub)[i] = uo;
  }
}

// ---------------- Kernel 2: LayerNorm -> bf16 h_out ----------------
__global__ void ln_kernel(const float* __restrict__ x, const float* __restrict__ gamma,
                          const float* __restrict__ beta, unsigned short* __restrict__ hout) {
  int row = blockIdx.x;
  int t = threadIdx.x;
  int wid = t >> 6, lane = t & 63;
  float4 v = ((const float4*)(x + (size_t)row * DD))[t];
  float s = v.x + v.y + v.z + v.w;
  float s2 = v.x * v.x + v.y * v.y + v.z * v.z + v.w * v.w;
  for (int o = 32; o; o >>= 1) { s += __shfl_down(s, o); s2 += __shfl_down(s2, o); }
  __shared__ float rs[4], rq[4];
  if (lane == 0) { rs[wid] = s; rq[wid] = s2; }
  __syncthreads();
  float sum = rs[0] + rs[1] + rs[2] + rs[3];
  float sum2 = rq[0] + rq[1] + rq[2] + rq[3];
  float mean = sum * (1.0f / DD);
  float var = sum2 * (1.0f / DD) - mean * mean;
  float rstd = rsqrtf(var + 1e-5f);
  float4 g = ((const float4*)gamma)[t];
  float4 bt = ((const float4*)beta)[t];
  ushort4_t o4;
  o4[0] = f2bf((v.x - mean) * rstd * g.x + bt.x);
  o4[1] = f2bf((v.y - mean) * rstd * g.y + bt.y);
  o4[2] = f2bf((v.z - mean) * rstd * g.z + bt.z);
  o4[3] = f2bf((v.w - mean) * rstd * g.w + bt.w);
  ((ushort4_t*)(hout + (size_t)row * DD))[t] = o4;
}

// ---------------- Kernel 3: GEMM xW = hout . W_w^T + b, 64 rows/block (R8, proven) ----------------
__launch_bounds__(256)
__global__ void gemm_xw(const unsigned short* __restrict__ A, const unsigned short* __restrict__ Bm,
                        const float* __restrict__ bias, unsigned short* __restrict__ xw) {
  int rowTile = blockIdx.x;   // 0..255, 64 rows each
  int colGrp = blockIdx.y;    // 0..15
  int wid = threadIdx.x >> 6;
  int lane = threadIdx.x & 63;
  int colBase = colGrp * 256 + wid * 64;
  int r0 = rowTile * 64 + (lane & 15);
  int kb = (lane >> 4) * 8;
  f32x4 acc[4][4] = {};
  for (int k0 = 0; k0 < DD; k0 += 32) {
    short8 af[4];
#pragma unroll
    for (int rr = 0; rr < 4; rr++)
      af[rr] = *(const short8*)(A + (size_t)(r0 + rr * 16) * DD + k0 + kb);
#pragma unroll
    for (int c = 0; c < 4; c++) {
      int col = colBase + c * 16 + (lane & 15);
      short8 bf = *(const short8*)(Bm + (size_t)col * DD + k0 + kb);
#pragma unroll
      for (int rr = 0; rr < 4; rr++)
        acc[rr][c] = __builtin_amdgcn_mfma_f32_16x16x32_bf16(af[rr], bf, acc[rr][c], 0, 0, 0);
    }
  }
#pragma unroll
  for (int rr = 0; rr < 4; rr++) {
#pragma unroll
    for (int c = 0; c < 4; c++) {
      int col = colBase + c * 16 + (lane & 15);
      float bv = bias[col];
#pragma unroll
      for (int r2 = 0; r2 < 4; r2++) {
        int R = rowTile * 64 + rr * 16 + (lane >> 4) * 4 + r2;
        int b = R >> 11, sIdx = R & 2047;
        xw[(size_t)sIdx * (BB * EE) + (size_t)b * EE + col] = f2bf(acc[rr][c][r2] + bv);
      }
    }
  }
}

// ---------------- Kernel 4: sLSTM scan — byte-exact R7 configuration (best measured) ----------------
// 64 blocks x 256 thr (4 waves). Block bl owns d in [bl*16, bl*16+16).
// Wave g owns gate g (16 e-cols), U slice register-resident.
// Protocol: coherent relaxed agent atomics for all cross-block data; all-wave
// flag poll; LDS h-stage (16 x 4B coherent loads, XOR swizzle); post-barrier
// activations in 128 update threads; release = vmcnt(0); barrier; flag; out.
__launch_bounds__(256, 1)
__global__ void scan_kernel(const unsigned short* __restrict__ xw, const unsigned short* __restrict__ Ub,
                            const float* __restrict__ x, float* __restrict__ out,
                            unsigned short* __restrict__ hbuf, int* __restrict__ flags) {
  int bl = blockIdx.x;
  int tid = threadIdx.x;
  int wid = tid >> 6, lane = tid & 63;
  int d0 = bl * 16;

  __shared__ __align__(16) unsigned short h_lds[8 * 1024];  // 16KB, XOR-swizzled
  __shared__ float g_lds[4][8][16];
  __shared__ char pad_lds[80 * 1024];   // occupancy limiter: 1 block/CU -> big reg budget
  ((volatile char*)pad_lds)[tid] = 0;   // keep allocation alive

  // preload U fragments: wave wid, e-cols wid*1024 + d0 + 0..15 -> 32 x short8
  int ecol = wid * 1024 + d0 + (lane & 15);
  int kb = (lane >> 4) * 8;
  short8 u[32];
#pragma unroll
  for (int kk = 0; kk < 32; kk++)
    u[kk] = *(const short8*)(Ub + (size_t)ecol * DD + kk * 32 + kb);
#pragma unroll
  for (int kk = 0; kk < 32; kk++)
    asm volatile("" : "+v"(u[kk]));  // pin; forbid remat/reload

  float c_s = 0.0f, n_s = 1.0f;
  int ub = tid >> 4, ud = tid & 15;  // update-thread coords (tid < 128)
  bool upd = tid < BB * 16;
  int arow = lane & 7;               // A rows 8..15 duplicate 0..7 (C rows 8..15 unused)
  int bq = (lane >> 4) * 4;          // C-frag batch base

  for (int s = 0; s < SS; s++) {
    // ---- prefetch step-s operands (independent of h) before the poll ----
    const unsigned short* xwp = xw + (size_t)s * (BB * EE) + (size_t)wid * 1024 + d0 + (lane & 15);
    unsigned short xv[4] = {0, 0, 0, 0};
    if (bq < BB) {
#pragma unroll
      for (int r2 = 0; r2 < 4; r2++) xv[r2] = xwp[(size_t)(bq + r2) * EE];
    }
    float xin = 0.0f;
    size_t oi = 0;
    if (upd) {
      oi = (size_t)ub * (SS * DD) + (size_t)s * DD + d0 + ud;
      xin = x[oi];
    }

    // ---- one-sided wait: all 64 block flags >= s (coherent relaxed loads) ----
    if (s != 0) {
      int f = __hip_atomic_load(flags + lane * 32, __ATOMIC_RELAXED, __HIP_MEMORY_SCOPE_AGENT);
      while (__any(f < s)) {
        f = __hip_atomic_load(flags + lane * 32, __ATOMIC_RELAXED, __HIP_MEMORY_SCOPE_AGENT);
      }
    }

    // ---- stage h (8 x 1024 bf16 = 16KB) -> swizzled LDS via coherent dword loads ----
    {
      const unsigned int* hg = (const unsigned int*)(hbuf + (size_t)(s & 1) * (BB * DD));
      unsigned int tmp[16];
#pragma unroll
      for (int i = 0; i < 16; i++)
        tmp[i] = __hip_atomic_load(hg + tid + i * 256, __ATOMIC_RELAXED, __HIP_MEMORY_SCOPE_AGENT);
#pragma unroll
      for (int i = 0; i < 16; i++) {
        int dw = tid + i * 256;              // 0..4095
        int row = dw >> 9;                   // 512 dwords per 2KB row
        int byte = (row * 2048 + (dw & 511) * 4) ^ (row << 4);
        *(unsigned int*)((char*)h_lds + byte) = tmp[i];
      }
    }
    __syncthreads();

    // ---- gates = h @ U^T : 32 MFMAs, 4 independent chains ----
    f32x4 a0 = {}, a1 = {}, a2 = {}, a3 = {};
#pragma unroll
    for (int kk = 0; kk < 32; kk += 4) {
      int base = arow * 2048 + (kk * 32 + kb) * 2;
      short8 f0 = *(const short8*)((char*)h_lds + ((base) ^ (arow << 4)));
      short8 f1 = *(const short8*)((char*)h_lds + ((base + 64) ^ (arow << 4)));
      short8 f2 = *(const short8*)((char*)h_lds + ((base + 128) ^ (arow << 4)));
      short8 f3 = *(const short8*)((char*)h_lds + ((base + 192) ^ (arow << 4)));
      a0 = __builtin_amdgcn_mfma_f32_16x16x32_bf16(f0, u[kk], a0, 0, 0, 0);
      a1 = __builtin_amdgcn_mfma_f32_16x16x32_bf16(f1, u[kk + 1], a1, 0, 0, 0);
      a2 = __builtin_amdgcn_mfma_f32_16x16x32_bf16(f2, u[kk + 2], a2, 0, 0, 0);
      a3 = __builtin_amdgcn_mfma_f32_16x16x32_bf16(f3, u[kk + 3], a3, 0, 0, 0);
    }
    f32x4 acc = (a0 + a1) + (a2 + a3);

    // ---- publish gates (valid batches) ----
    if (bq < BB) {
#pragma unroll
      for (int r2 = 0; r2 < 4; r2++)
        g_lds[wid][bq + r2][lane & 15] = acc[r2] + bf2f(xv[r2]);
    }
    __syncthreads();

    // ---- state update (128 thr, 1 d each) + coherent h publish; release = vmcnt(0) ----
    float h_val = 0.0f;
    if (upd) {
      float gi = g_lds[0][ub][ud], gf = g_lds[1][ub][ud];
      float go = g_lds[2][ub][ud], gz = g_lds[3][ub][ud];
      float it = __expf(gi);
      float ft = 1.0f / (1.0f + __expf(-gf));
      float ot = 1.0f / (1.0f + __expf(-go));
      float az = fabsf(gz);
      float e2 = __expf(2.0f * az);
      float zt = __builtin_copysignf(1.0f - 2.0f / (e2 + 1.0f), gz);
      c_s = ft * c_s + it * zt;
      n_s = ft * n_s + it;
      h_val = ot * (c_s / (n_s + 1e-6f));
      __hip_atomic_store(hbuf + (size_t)((s + 1) & 1) * (BB * DD) + ub * DD + d0 + ud,
                         f2bf(h_val), __ATOMIC_RELAXED, __HIP_MEMORY_SCOPE_AGENT);
      asm volatile("s_waitcnt vmcnt(0)" ::: "memory");  // drain coherent h stores
    }
    __syncthreads();     // all waves joined after stores drained
    if (tid == 0)
      __hip_atomic_store(flags + bl * 32, s + 1, __ATOMIC_RELAXED, __HIP_MEMORY_SCOPE_AGENT);
    // ---- fused output write: off the cross-block critical path ----
    if (upd)
      __builtin_nontemporal_store(xin + h_val, out + oi);
  }
}

// ---------------- launch ----------------
extern "C" void kernel_launch(void* const* d_in, const int* in_sizes, int n_in,
                              void* d_out, int out_size, void* d_ws, size_t ws_size,
                              hipStream_t stream) {
  const float* xp = (const float*)d_in[0];
  const float* Wwf = (const float*)d_in[1];
  const float* Wbias = (const float*)d_in[2];
  const float* Uwf = (const float*)d_in[3];
  const float* gamma = (const float*)d_in[4];
  const float* beta = (const float*)d_in[5];
  float* outp = (float*)d_out;

  char* w = (char*)d_ws;
  unsigned short* Wb = (unsigned short*)(w);                 // 8 MB
  unsigned short* Ub = (unsigned short*)(w + 8388608);       // 8 MB
  unsigned short* hout = (unsigned short*)(w + 16777216);    // 32 MB
  unsigned short* xw = (unsigned short*)(w + 50331648);      // 128 MB
  unsigned short* hbuf = (unsigned short*)(w + 184549376);   // 32 KB (2 x 8 x 1024 bf16)
  int* flags = (int*)(w + 184549376 + 32768);                // 64 flags, 128B apart

  hipMemsetAsync((void*)hbuf, 0, 32768 + 8192, stream);      // zero h state + flags every call

  hipLaunchKernelGGL(cvt2_kernel, dim3(1024), dim3(256), 0, stream, Wwf, Uwf, Wb, Ub);
  hipLaunchKernelGGL(ln_kernel, dim3(BB * SS), dim3(256), 0, stream, xp, gamma, beta, hout);
  hipLaunchKernelGGL(gemm_xw, dim3(256, 16), dim3(256), 0, stream, hout, Wb, Wbias, xw);

  void* args[6];
  const unsigned short* xw_c = xw;
  const unsigned short* ub_c = Ub;
  args[0] = (void*)&xw_c;
  args[1] = (void*)&ub_c;
  args[2] = (void*)&xp;
  args[3] = (void*)&outp;
  args[4] = (void*)&hbuf;
  args[5] = (void*)&flags;
  hipLaunchCooperativeKernel((void*)scan_kernel, dim3(NB), dim3(256), args, 0, stream);
}